// Round 10
// baseline (310.253 us; speedup 1.0000x reference)
//
#include <hip/hip_runtime.h>

#define B_   4
#define C_   512
#define S_   4096
#define G_   32
#define CPG_ 16
#define EPS_ 1e-6f

typedef unsigned short u16;
typedef __bf16 bf16x8 __attribute__((ext_vector_type(8)));
typedef float  f32x4  __attribute__((ext_vector_type(4)));

__device__ __forceinline__ u16 f2bf(float f) {
  unsigned u = __float_as_uint(f);
  u += 0x7fffu + ((u >> 16) & 1u);   // RNE
  return (u16)(u >> 16);
}
__device__ __forceinline__ float bf2f(u16 h) {
  return __uint_as_float((unsigned)h << 16);
}

__device__ __forceinline__ void g2lds16(const void* g, void* l) {
  __builtin_amdgcn_global_load_lds(
      (const __attribute__((address_space(1))) void*)g,
      (__attribute__((address_space(3))) void*)l, 16, 0, 0);
}

#define BAR()    __builtin_amdgcn_s_barrier()
#define SCHED0() __builtin_amdgcn_sched_barrier(0)
#define WAITV4   asm volatile("s_waitcnt vmcnt(4)" ::: "memory")
#define WAITV0   asm volatile("s_waitcnt vmcnt(0)" ::: "memory")

// chunked XCD swizzle (bijective when nwg % 8 == 0 — all grids here satisfy it)
__device__ __forceinline__ void xcd_swz(int& bx, int& by, int& bz) {
  const int gx = gridDim.x, gy = gridDim.y;
  const int nwg = gx * gy * (int)gridDim.z;
  const int flat = blockIdx.x + gx * (blockIdx.y + gy * blockIdx.z);
  const int q = nwg >> 3;
  const int nf = (flat & 7) * q + (flat >> 3);
  bx = nf % gx;
  const int r = nf / gx;
  by = r % gy;
  bz = r / gy;
}

// ---------------- fp32 -> bf16 weight conversion ----------------
__global__ __launch_bounds__(256) void f32_to_bf16(const float* __restrict__ in,
                                                   u16* __restrict__ out, int n) {
  int i = blockIdx.x * 256 + threadIdx.x;
  if (i < n) out[i] = f2bf(in[i]);
}

__global__ __launch_bounds__(256) void concat_bias(const float* __restrict__ a,
                                                   const float* __restrict__ b,
                                                   float* __restrict__ o) {
  int i = blockIdx.x * 256 + threadIdx.x;  // grid 4 -> 1024
  o[i] = (i < 512) ? a[i] : b[i - 512];
}

// -------- softmax denominator: Lr[b,i] = 1/sum over 64 partials --------
__global__ __launch_bounds__(256) void reduce_l(const float* __restrict__ p,
                                                float* __restrict__ lr) {
  const int i = blockIdx.x * 256 + threadIdx.x;   // 16384 = B*S
  const int b = i >> 12, row = i & 4095;
  float s = 0.f;
#pragma unroll
  for (int jb = 0; jb < 16; ++jb)
#pragma unroll
    for (int w = 0; w < 4; ++w)
      s += p[(((size_t)(b * 16 + jb) * 4 + w) << 12) + row];
  lr[i] = 1.f / s;
}

// -------- PV split-K reduce + softmax normalize: o = (a+b)*Lr[row] --------
__global__ __launch_bounds__(256) void add_scale_bf16(const u16* __restrict__ a,
                                                      const u16* __restrict__ b,
                                                      const float* __restrict__ lr,
                                                      u16* __restrict__ o) {
  const int i = blockIdx.x * 256 + threadIdx.x;   // uint4 index (8 bf16)
  const size_t i8 = (size_t)i * 8;
  const int bi = (int)(i8 >> 21);          // 2M bf16 per batch
  const int row = (int)(i8 >> 9) & 4095;   // 512 bf16 per row
  const float sc = lr[bi * 4096 + row];
  const uint4 ua = ((const uint4*)a)[i];
  const uint4 ub = ((const uint4*)b)[i];
  const unsigned* pa = (const unsigned*)&ua;
  const unsigned* pb = (const unsigned*)&ub;
  unsigned r[4];
#pragma unroll
  for (int k = 0; k < 4; ++k) {
    const float lo = (bf2f((u16)(pa[k] & 0xffffu)) + bf2f((u16)(pb[k] & 0xffffu))) * sc;
    const float hi = (bf2f((u16)(pa[k] >> 16)) + bf2f((u16)(pb[k] >> 16))) * sc;
    r[k] = (unsigned)f2bf(lo) | ((unsigned)f2bf(hi) << 16);
  }
  ((uint4*)o)[i] = *(const uint4*)r;
}

// ---------------- GroupNorm stats: one block per (b,g) ----------------
__global__ __launch_bounds__(256) void gn_stats(const float* __restrict__ x,
                                                float* __restrict__ stats) {
  const int bg = blockIdx.x;
  const float4* p4 = (const float4*)(x + (size_t)bg * (CPG_ * S_));
  float s = 0.f, ss = 0.f;
  const int tid = threadIdx.x;
  for (int i = tid; i < CPG_ * S_ / 4; i += 256) {
    float4 v = p4[i];
    s  += v.x + v.y + v.z + v.w;
    ss += v.x * v.x + v.y * v.y + v.z * v.z + v.w * v.w;
  }
#pragma unroll
  for (int o = 32; o; o >>= 1) { s += __shfl_xor(s, o, 64); ss += __shfl_xor(ss, o, 64); }
  __shared__ float sm[8];
  const int wid = tid >> 6, lane = tid & 63;
  if (lane == 0) { sm[wid * 2] = s; sm[wid * 2 + 1] = ss; }
  __syncthreads();
  if (tid == 0) {
    s  = sm[0] + sm[2] + sm[4] + sm[6];
    ss = sm[1] + sm[3] + sm[5] + sm[7];
    const float inv = 1.f / (float)(CPG_ * S_);
    float mu = s * inv;
    float var = ss * inv - mu * mu;
    stats[bg * 2]     = mu;
    stats[bg * 2 + 1] = rsqrtf(var + EPS_);
  }
}

// ---------------- normalize + transpose: x[b,c,s] -> ht[b*s, c] bf16 ----------------
__global__ __launch_bounds__(256) void gn_apply_t(const float* __restrict__ x,
                                                  const float* __restrict__ gamma,
                                                  const float* __restrict__ beta,
                                                  const float* __restrict__ stats,
                                                  u16* __restrict__ ht) {
  __shared__ float tile[32][33];
  const int b = blockIdx.z, c0 = blockIdx.y * 32, s0 = blockIdx.x * 32;
  const int tx = threadIdx.x, ty = threadIdx.y;
#pragma unroll
  for (int i = 0; i < 4; ++i) {
    const int c  = c0 + ty + i * 8;
    const float mu = stats[(b * G_ + (c >> 4)) * 2];
    const float rs = stats[(b * G_ + (c >> 4)) * 2 + 1];
    const float v  = x[((size_t)b * C_ + c) * S_ + s0 + tx];
    tile[ty + i * 8][tx] = (v - mu) * rs * gamma[c] + beta[c];
  }
  __syncthreads();
#pragma unroll
  for (int i = 0; i < 4; ++i) {
    const int s = s0 + ty + i * 8;
    ht[((size_t)b * S_ + s) * C_ + c0 + tx] = f2bf(tile[tx][ty + i * 8]);
  }
}

// ================= 256x256 4-phase GEMM (R3 structure — measured best) =================
// C[m,n] = alpha * sum_k A[m,k]*B[n,k] (+bias[n]); A,B bf16 K-contiguous.
// 512 thr = 8 waves (2m x 4n), per-wave 128x64 CONTIGUOUS (8x4 frags of 16x16x32).
// LDS: 4-slot K-half ring per operand, slot [256 rows][32 u16], swizzle phys
// granule = g ^ ((row>>1)&3) (measured 0-conflict). Staged via global_load_lds
// with pre-swizzled source. 4 phases/K-tile: (kh0,mh0)(kh0,mh1)(kh1,mh0)(kh1,mh1);
// B-frags read once per kh, held in regs. One stage-quarter (2 gloads) per phase.
// Counted WAITV4 BEFORE the barrier at P0/P2 (drains the stages for the slot about
// to be read; all waves drain-then-barrier -> cross-wave visibility safe, R6 rule).
// NO explicit lgkmcnt: compiler emits fine-grained lgkmcnt(N) per frag (m97 lesson).
// ZMODE 1 = PV split-K: bz -> (b=bz>>1, kh=bz&1), hardcoded offsets.
// SMAX 1 = scores epilogue: P=exp(alpha*s) bf16 + per-wave row-sum partials -> smx.
#define STAGE_A(T, KS) do {                                                  \
    const int _sl = (2 * (T) + (KS)) & 3;                                    \
    const size_t _ko = (size_t)(T) * 64 + (KS) * 32;                         \
    g2lds16(Asrc + _ko,  &As[_sl][wid * 512]);                               \
    g2lds16(Asrc2 + _ko, &As[_sl][4096 + wid * 512]);                        \
  } while (0)
#define STAGE_B(T, KS) do {                                                  \
    const int _sl = (2 * (T) + (KS)) & 3;                                    \
    const size_t _ko = (size_t)(T) * 64 + (KS) * 32;                         \
    g2lds16(Bsrc + _ko,  &Bs[_sl][wid * 512]);                               \
    g2lds16(Bsrc2 + _ko, &Bs[_sl][4096 + wid * 512]);                        \
  } while (0)
#define LDB4(SL)                                                             \
  _Pragma("unroll") for (int i = 0; i < 4; ++i)                              \
      bfr[i] = *(const bf16x8*)&Bs[(SL)][bbase + i * 512];
#define LDA4(SL, MH)                                                         \
  _Pragma("unroll") for (int i = 0; i < 4; ++i)                              \
      af[i] = *(const bf16x8*)&As[(SL)][abase + ((MH) * 4 + i) * 512];
#define MFMA16(MH) do {                                                      \
    __builtin_amdgcn_s_setprio(1);                                           \
    _Pragma("unroll") for (int mi = 0; mi < 4; ++mi)                         \
    _Pragma("unroll") for (int ni = 0; ni < 4; ++ni)                         \
      acc[(MH) * 4 + mi][ni] = __builtin_amdgcn_mfma_f32_16x16x32_bf16(      \
          af[mi], bfr[ni], acc[(MH) * 4 + mi][ni], 0, 0, 0);                 \
    __builtin_amdgcn_s_setprio(0);                                           \
  } while (0)

template <int BIAS_MODE, int ZMODE, int SMAX>
__global__ __launch_bounds__(512, 2) void gemm256(
    const u16* __restrict__ Ag, int lda, long sA,
    const u16* __restrict__ Bg, int ldb, long sB,
    u16* __restrict__ Cg, int ldc, long sC,
    const float* __restrict__ bias, float alpha, int K,
    float* __restrict__ smx) {
  __shared__ u16 As[4][8192];
  __shared__ u16 Bs[4][8192];
  int bx, by, bz;
  xcd_swz(bx, by, bz);
  const u16 *A, *Bm;
  u16* Cb;
  if (ZMODE == 0) {
    A = Ag + (size_t)bz * sA; Bm = Bg + (size_t)bz * sB; Cb = Cg + (size_t)bz * sC;
  } else {  // PV split-K: A = P[b], cols kh*2048+; B = V rows, cols b*4096+kh*2048+
    const int b = bz >> 1, kh = bz & 1;
    A  = Ag + (size_t)b * 16777216 + (size_t)kh * 2048;
    Bm = Bg + (size_t)b * 4096 + (size_t)kh * 2048;
    Cb = Cg + (size_t)kh * 8388608 + (size_t)b * 2097152;
  }
  const int bm = by * 256, bn = bx * 256;
  const int tid = threadIdx.x;
  const int wid = tid >> 6, lane = tid & 63;
  const int wm = (wid >> 2) * 128, wn = (wid & 3) * 64;
  const int lr = lane & 15, lh = lane >> 4;

  // staging: lane covers (row = wid*16 + lane>>2 [+128], phys granule lane&3)
  const int srow = wid * 16 + (lane >> 2);
  const int sg   = (lane & 3) ^ ((srow >> 1) & 3);
  const u16* Asrc  = A  + (size_t)(bm + srow) * lda + sg * 8;
  const u16* Asrc2 = Asrc + (size_t)128 * lda;
  const u16* Bsrc  = Bm + (size_t)(bn + srow) * ldb + sg * 8;
  const u16* Bsrc2 = Bsrc + (size_t)128 * ldb;

  const int swz   = (lh ^ ((lr >> 1) & 3)) << 3;
  const int abase = (wm + lr) * 32 + swz;
  const int bbase = (wn + lr) * 32 + swz;

  // bias preload BEFORE staging: ledger stays exact (first WAITV4 drains
  // bias(4) + kh0 stages(4), leaving kh1's 4 in flight)
  float bias_v[4] = {0.f, 0.f, 0.f, 0.f};
  if (BIAS_MODE == 1) {
#pragma unroll
    for (int nf = 0; nf < 4; ++nf) bias_v[nf] = bias[bn + wn + nf * 16 + lr];
  }
  SCHED0();

  f32x4 acc[8][4];
  const f32x4 zero = {0.f, 0.f, 0.f, 0.f};
#pragma unroll
  for (int i = 0; i < 8; ++i)
#pragma unroll
    for (int j = 0; j < 4; ++j) acc[i][j] = zero;

  STAGE_A(0, 0); STAGE_B(0, 0); STAGE_A(0, 1); STAGE_B(0, 1);

  const int nt = K >> 6;
  for (int t = 0; t < nt; ++t) {
    const int s0 = (2 * t) & 3, s1 = s0 + 1;
    const bool pre = (t + 1 < nt);
    bf16x8 bfr[4], af[4];
    // ---- P0 (kh0, mh0): drain t's kh0 stages (before barrier -> race-safe)
    WAITV4;
    BAR(); SCHED0();
    LDB4(s0);
    LDA4(s0, 0);
    if (pre) STAGE_A(t + 1, 0);
    MFMA16(0);
    // ---- P1 (kh0, mh1): reuse bfr
    BAR(); SCHED0();
    LDA4(s0, 1);
    if (pre) STAGE_B(t + 1, 0);
    MFMA16(1);
    // ---- P2 (kh1, mh0): drain t's kh1 stages
    if (pre) { WAITV4; } else { WAITV0; }
    BAR(); SCHED0();
    LDB4(s1);
    LDA4(s1, 0);
    if (pre) STAGE_A(t + 1, 1);
    MFMA16(0);
    // ---- P3 (kh1, mh1)
    BAR(); SCHED0();
    LDA4(s1, 1);
    if (pre) STAGE_B(t + 1, 1);
    MFMA16(1);
  }
  SCHED0();

  if (SMAX) {
    // P = exp(alpha*s) bf16 out + per-wave row-sum partials straight to global
    float rs[8][4];
#pragma unroll
    for (int mf = 0; mf < 8; ++mf) {
      const int row0 = bm + wm + mf * 16 + lh * 4;
#pragma unroll
      for (int r = 0; r < 4; ++r) rs[mf][r] = 0.f;
#pragma unroll
      for (int nf = 0; nf < 4; ++nf) {
        const int col = bn + wn + nf * 16 + lr;
#pragma unroll
        for (int r = 0; r < 4; ++r) {
          const float e = __expf(acc[mf][nf][r] * alpha);
          rs[mf][r] += e;
          Cb[(size_t)(row0 + r) * ldc + col] = f2bf(e);
        }
      }
    }
#pragma unroll
    for (int mf = 0; mf < 8; ++mf)
#pragma unroll
      for (int r = 0; r < 4; ++r) {
        float v = rs[mf][r];
        v += __shfl_xor(v, 1, 64);
        v += __shfl_xor(v, 2, 64);
        v += __shfl_xor(v, 4, 64);
        v += __shfl_xor(v, 8, 64);
        if (lr == 0)
          smx[(((size_t)bz * 16 + bx) * 4 + (wid & 3)) * 4096 +
              bm + wm + mf * 16 + lh * 4 + r] = v;
      }
  } else {
#pragma unroll
    for (int mf = 0; mf < 8; ++mf) {
      const int row0 = bm + wm + mf * 16 + lh * 4;
#pragma unroll
      for (int nf = 0; nf < 4; ++nf) {
        const int col = bn + wn + nf * 16 + lr;
#pragma unroll
        for (int r = 0; r < 4; ++r)
          Cb[(size_t)(row0 + r) * ldc + col] = f2bf(acc[mf][nf][r] * alpha + bias_v[nf]);
      }
    }
  }
}

// ---------------- old 128x128 GEMM (kept for V-proj and out-proj) ----------------
#define GBM 128
#define GBN 128
#define GBK 64

template <int BIAS_MODE, int OUT_MODE>
__global__ __launch_bounds__(256) void gemm_abT(
    const u16* __restrict__ Ag, int lda, long sA,
    const u16* __restrict__ Bg, int ldb, long sB,
    void* __restrict__ Cg, int ldc, long sC,
    const float* __restrict__ bias, float alpha,
    const float* __restrict__ xres, int K) {
  __shared__ u16 As[GBM * GBK];
  __shared__ u16 Bs[GBN * GBK];
  const int bz = blockIdx.z;
  const u16* A    = Ag + (size_t)bz * sA;
  const u16* Bmat = Bg + (size_t)bz * sB;
  const int bm = blockIdx.y * GBM, bn = blockIdx.x * GBN;
  const int tid = threadIdx.x;
  const int wid = tid >> 6, lane = tid & 63;
  const int wm = (wid >> 1) * 64, wn = (wid & 1) * 64;
  const int lr = lane & 15, lh = lane >> 4;
  const int srow = lane >> 3, scol = (lane & 7) * 8;

  f32x4 acc[4][4];
  const f32x4 zero = {0.f, 0.f, 0.f, 0.f};
#pragma unroll
  for (int i = 0; i < 4; ++i)
#pragma unroll
    for (int j = 0; j < 4; ++j) acc[i][j] = zero;

  for (int k0 = 0; k0 < K; k0 += GBK) {
    __syncthreads();
#pragma unroll
    for (int i = 0; i < 4; ++i) {
      const int chunk = wid * 4 + i;
      const int row   = chunk * 8 + srow;
      g2lds16(A    + (size_t)(bm + row) * lda + (k0 + scol), &As[chunk * 512]);
      g2lds16(Bmat + (size_t)(bn + row) * ldb + (k0 + scol), &Bs[chunk * 512]);
    }
    __syncthreads();
#pragma unroll
    for (int ks = 0; ks < 2; ++ks) {
      bf16x8 a_[4], b_[4];
#pragma unroll
      for (int m = 0; m < 4; ++m)
        a_[m] = *(const bf16x8*)&As[(wm + m * 16 + lr) * GBK + ks * 32 + lh * 8];
#pragma unroll
      for (int n = 0; n < 4; ++n)
        b_[n] = *(const bf16x8*)&Bs[(wn + n * 16 + lr) * GBK + ks * 32 + lh * 8];
#pragma unroll
      for (int m = 0; m < 4; ++m)
#pragma unroll
        for (int n = 0; n < 4; ++n)
          acc[m][n] = __builtin_amdgcn_mfma_f32_16x16x32_bf16(a_[m], b_[n], acc[m][n], 0, 0, 0);
    }
  }

  if (OUT_MODE == 0) {
    u16* Cb = (u16*)Cg + (size_t)bz * sC;
#pragma unroll
    for (int m = 0; m < 4; ++m) {
      const int row0 = bm + wm + m * 16 + lh * 4;
#pragma unroll
      for (int n = 0; n < 4; ++n) {
        const int col = bn + wn + n * 16 + lr;
        float bn_ = (BIAS_MODE == 1) ? bias[col] : 0.f;
#pragma unroll
        for (int r = 0; r < 4; ++r) {
          float bb = (BIAS_MODE == 2) ? bias[row0 + r] : bn_;
          Cb[(size_t)(row0 + r) * ldc + col] = f2bf(acc[m][n][r] * alpha + bb);
        }
      }
    }
  } else {
    float* Ob = (float*)Cg;
#pragma unroll
    for (int m = 0; m < 4; ++m) {
      const int row0 = bm + wm + m * 16 + lh * 4;
#pragma unroll
      for (int n = 0; n < 4; ++n) {
        const int col = bn + wn + n * 16 + lr;
        const int bb = col >> 12, sp = col & (S_ - 1);
#pragma unroll
        for (int r = 0; r < 4; ++r) {
          const int o = row0 + r;
          const size_t idx = ((size_t)bb * C_ + o) * S_ + sp;
          Ob[idx] = acc[m][n][r] * alpha + bias[o] + xres[idx];
        }
      }
    }
  }
}

extern "C" void kernel_launch(void* const* d_in, const int* in_sizes, int n_in,
                              void* d_out, int out_size, void* d_ws, size_t ws_size,
                              hipStream_t stream) {
  const float* x     = (const float*)d_in[0];
  const float* gamma = (const float*)d_in[1];
  const float* beta  = (const float*)d_in[2];
  const float* wq = (const float*)d_in[3];
  const float* bq = (const float*)d_in[4];
  const float* wk = (const float*)d_in[5];
  const float* bk = (const float*)d_in[6];
  const float* wv = (const float*)d_in[7];
  const float* bv = (const float*)d_in[8];
  const float* wo = (const float*)d_in[9];
  const float* bo = (const float*)d_in[10];
  float* out = (float*)d_out;

  // ws: stats 1KB | weights bf16 4x512KB | bqk 4KB | ht 16MB | qkt 32MB | vv 16MB
  //     | sc 128MB.  partials(4MB)+Lr overlay ht (dead after V-proj).
  char* ws = (char*)d_ws;
  float* stats = (float*)ws;
  u16* wqb = (u16*)(ws + 1024);
  u16* wkb = wqb + 262144;   // contiguous after wqb -> [wq;wk] is one 1024x512 matrix
  u16* wvb = wkb + 262144;
  u16* wob = wvb + 262144;
  float* bqk = (float*)(wob + 262144);
  u16* ht  = (u16*)((char*)bqk + 4096);  // [B*S, C]
  u16* qkt = ht + 8388608;               // [B*S, 1024] (q|k); later PV psum halves
  u16* vv  = qkt + 16777216;             // [C, B*S]; later normalized hattnT
  u16* sc  = vv + 8388608;               // [B, S, S] exp(scores)
  float* partials = (float*)ht;          // [B][16][4][4096] overlays dead ht
  float* Lr = partials + 1048576;        // [B][4096]

  f32_to_bf16<<<1024, 256, 0, stream>>>(wq, wqb, 262144);
  f32_to_bf16<<<1024, 256, 0, stream>>>(wk, wkb, 262144);
  f32_to_bf16<<<1024, 256, 0, stream>>>(wv, wvb, 262144);
  f32_to_bf16<<<1024, 256, 0, stream>>>(wo, wob, 262144);
  concat_bias<<<4, 256, 0, stream>>>(bq, bk, bqk);

  gn_stats<<<128, 256, 0, stream>>>(x, stats);
  gn_apply_t<<<dim3(128, 16, 4), dim3(32, 8), 0, stream>>>(x, gamma, beta, stats, ht);

  // fused Q|K projection: qkt[bs, 0:512]=Q, [512:1024]=K   (256 blocks)
  gemm256<1, 0, 0><<<dim3(4, 64, 1), 512, 0, stream>>>(ht, 512, 0, wqb, 512, 0,
                                                       qkt, 1024, 0, bqk, 1.f, 512, nullptr);
  // V[c, b*S+s]: bias per m (=c)                            (512 blocks)
  gemm_abT<2, 0><<<dim3(128, 4, 1), 256, 0, stream>>>(wvb, 512, 0, ht, 512, 0,
                                                      vv, 16384, 0, bv, 1.f, nullptr, 512);
  // P[b,i,j] = exp(scale * Q.K) + per-wave row-sum partials (1024 blocks)
  gemm256<0, 0, 1><<<dim3(16, 16, 4), 512, 0, stream>>>(qkt, 1024, 4194304, qkt + 512, 1024, 4194304,
                                                        sc, 4096, 16777216, nullptr,
                                                        0.04419417382415922f, 512, partials);
  reduce_l<<<64, 256, 0, stream>>>(partials, Lr);
  // PV split-K=2 on unnormalized P: psums in qkt halves     (256 blocks)
  gemm256<0, 1, 0><<<dim3(2, 16, 8), 512, 0, stream>>>(sc, 4096, 0, vv, 16384, 0,
                                                       qkt, 512, 0, nullptr, 1.f, 2048, nullptr);
  // combine psums + apply 1/l row scale -> normalized hattnT in vv
  add_scale_bf16<<<4096, 256, 0, stream>>>(qkt, qkt + 8388608, Lr, vv);
  // out[b,o,s] = Wo@hattn + bo + x  (fp32 + residual)       (512 blocks)
  gemm_abT<2, 1><<<dim3(128, 4, 1), 256, 0, stream>>>(wob, 512, 0, vv, 512, 0,
                                                      out, 0, 0, bo, 1.f, x, 512);
}

// Round 11
// 290.794 us; speedup vs baseline: 1.0669x; 1.0669x over previous
//
#include <hip/hip_runtime.h>

#define B_   4
#define C_   512
#define S_   4096
#define G_   32
#define CPG_ 16
#define EPS_ 1e-6f

typedef unsigned short u16;
typedef __bf16 bf16x8 __attribute__((ext_vector_type(8)));
typedef float  f32x4  __attribute__((ext_vector_type(4)));

__device__ __forceinline__ u16 f2bf(float f) {
  unsigned u = __float_as_uint(f);
  u += 0x7fffu + ((u >> 16) & 1u);   // RNE
  return (u16)(u >> 16);
}
__device__ __forceinline__ float bf2f(u16 h) {
  return __uint_as_float((unsigned)h << 16);
}

__device__ __forceinline__ void g2lds16(const void* g, void* l) {
  __builtin_amdgcn_global_load_lds(
      (const __attribute__((address_space(1))) void*)g,
      (__attribute__((address_space(3))) void*)l, 16, 0, 0);
}

#define BAR()    __builtin_amdgcn_s_barrier()
#define SCHED0() __builtin_amdgcn_sched_barrier(0)
#define WAITV4   asm volatile("s_waitcnt vmcnt(4)" ::: "memory")
#define WAITV0   asm volatile("s_waitcnt vmcnt(0)" ::: "memory")
#define LGKM0    asm volatile("s_waitcnt lgkmcnt(0)" ::: "memory")

// chunked XCD swizzle (bijective when nwg % 8 == 0 — all grids here satisfy it)
__device__ __forceinline__ void xcd_swz(int& bx, int& by, int& bz) {
  const int gx = gridDim.x, gy = gridDim.y;
  const int nwg = gx * gy * (int)gridDim.z;
  const int flat = blockIdx.x + gx * (blockIdx.y + gy * blockIdx.z);
  const int q = nwg >> 3;
  const int nf = (flat & 7) * q + (flat >> 3);
  bx = nf % gx;
  const int r = nf / gx;
  by = r % gy;
  bz = r / gy;
}

// ---------------- fp32 -> bf16 weight conversion ----------------
__global__ __launch_bounds__(256) void f32_to_bf16(const float* __restrict__ in,
                                                   u16* __restrict__ out, int n) {
  int i = blockIdx.x * 256 + threadIdx.x;
  if (i < n) out[i] = f2bf(in[i]);
}

__global__ __launch_bounds__(256) void concat_bias(const float* __restrict__ a,
                                                   const float* __restrict__ b,
                                                   float* __restrict__ o) {
  int i = blockIdx.x * 256 + threadIdx.x;  // grid 4 -> 1024
  o[i] = (i < 512) ? a[i] : b[i - 512];
}

// ---------------- softmax denominator: Lr[b,i] = 1/sum_jb partial ----------------
__global__ __launch_bounds__(256) void reduce_l(const float* __restrict__ p,
                                                float* __restrict__ lr) {
  const int i = blockIdx.x * 256 + threadIdx.x;   // 16384 = B*S
  const int b = i >> 12, row = i & 4095;
  float s = 0.f;
#pragma unroll
  for (int jb = 0; jb < 16; ++jb) s += p[((size_t)(b * 16 + jb) << 12) + row];
  lr[i] = 1.f / s;
}

// ---------------- GroupNorm stats: one block per (b,g) ----------------
__global__ __launch_bounds__(256) void gn_stats(const float* __restrict__ x,
                                                float* __restrict__ stats) {
  const int bg = blockIdx.x;
  const float4* p4 = (const float4*)(x + (size_t)bg * (CPG_ * S_));
  float s = 0.f, ss = 0.f;
  const int tid = threadIdx.x;
  for (int i = tid; i < CPG_ * S_ / 4; i += 256) {
    float4 v = p4[i];
    s  += v.x + v.y + v.z + v.w;
    ss += v.x * v.x + v.y * v.y + v.z * v.z + v.w * v.w;
  }
#pragma unroll
  for (int o = 32; o; o >>= 1) { s += __shfl_xor(s, o, 64); ss += __shfl_xor(ss, o, 64); }
  __shared__ float sm[8];
  const int wid = tid >> 6, lane = tid & 63;
  if (lane == 0) { sm[wid * 2] = s; sm[wid * 2 + 1] = ss; }
  __syncthreads();
  if (tid == 0) {
    s  = sm[0] + sm[2] + sm[4] + sm[6];
    ss = sm[1] + sm[3] + sm[5] + sm[7];
    const float inv = 1.f / (float)(CPG_ * S_);
    float mu = s * inv;
    float var = ss * inv - mu * mu;
    stats[bg * 2]     = mu;
    stats[bg * 2 + 1] = rsqrtf(var + EPS_);
  }
}

// ---------------- normalize + transpose: x[b,c,s] -> ht[b*s, c] bf16 ----------------
__global__ __launch_bounds__(256) void gn_apply_t(const float* __restrict__ x,
                                                  const float* __restrict__ gamma,
                                                  const float* __restrict__ beta,
                                                  const float* __restrict__ stats,
                                                  u16* __restrict__ ht) {
  __shared__ float tile[32][33];
  const int b = blockIdx.z, c0 = blockIdx.y * 32, s0 = blockIdx.x * 32;
  const int tx = threadIdx.x, ty = threadIdx.y;
#pragma unroll
  for (int i = 0; i < 4; ++i) {
    const int c  = c0 + ty + i * 8;
    const float mu = stats[(b * G_ + (c >> 4)) * 2];
    const float rs = stats[(b * G_ + (c >> 4)) * 2 + 1];
    const float v  = x[((size_t)b * C_ + c) * S_ + s0 + tx];
    tile[ty + i * 8][tx] = (v - mu) * rs * gamma[c] + beta[c];
  }
  __syncthreads();
#pragma unroll
  for (int i = 0; i < 4; ++i) {
    const int s = s0 + ty + i * 8;
    ht[((size_t)b * S_ + s) * C_ + c0 + tx] = f2bf(tile[tx][ty + i * 8]);
  }
}

// ================= 256x256 8-phase GEMM (R8 exact — best measured) =================
// C[m,n] = alpha * sum_k A[m,k]*B[n,k] (+bias[n]); A,B bf16 K-contiguous.
// 512 thr = 8 waves (2M x 4N), strided frags: m-frag f at wm+f*32, n-frag g at
// wn+g*64. LDS As/Bs[2 dbuf][2 half][128][64] u16; swizzle phys granule = g^(row&7).
// Ledger: counted vmcnt(4) drains BEFORE the end-barrier of p3/p7 (+prologue), so
// every staged-buffer read is {all-waves-drained -> barrier} protected. Steady
// state 12 loads in flight, drains to 4, never 0.
// ZMODE 1 = PV split-K: bz -> (b = bz>>1, kh = bz&1), hardcoded offsets.
// SMAX 1 = scores epilogue: write exp(alpha*acc) bf16 + per-block row-sum partials.
template <int BIAS_MODE, int ZMODE, int SMAX>
__global__ __launch_bounds__(512, 2) void gemm8p(
    const u16* __restrict__ Ag, int lda, long sA,
    const u16* __restrict__ Bg, int ldb, long sB,
    u16* __restrict__ Cg, int ldc, long sC,
    const float* __restrict__ bias, float alpha, int K,
    float* __restrict__ smx) {
  __shared__ u16 As[2][2][8192];
  __shared__ u16 Bs[2][2][8192];
  __shared__ float ps[4][256];
  int bx, by, bz;
  xcd_swz(bx, by, bz);
  const u16 *A, *Bm;
  u16* Cb;
  if (ZMODE == 0) {
    A = Ag + (size_t)bz * sA; Bm = Bg + (size_t)bz * sB; Cb = Cg + (size_t)bz * sC;
  } else {  // PV split-K: A = P[b], cols kh*2048+; B = V rows, cols b*4096+kh*2048+
    const int b = bz >> 1, kh = bz & 1;
    A  = Ag + (size_t)b * 16777216 + (size_t)kh * 2048;
    Bm = Bg + (size_t)b * 4096 + (size_t)kh * 2048;
    Cb = Cg + (size_t)kh * 8388608 + (size_t)b * 2097152;
  }
  const int bm = by * 256, bn = bx * 256;
  const int tid = threadIdx.x;
  const int wid = tid >> 6, lane = tid & 63;
  const int wm = (wid >> 2) * 16, wn = (wid & 3) * 16;
  const int lr = lane & 15, lh = lane >> 4;
  const int x7 = lr & 7;
  const int g0 = (lh ^ x7) * 8, g1 = ((4 | lh) ^ x7) * 8;  // swizzled granule offs (kh=0/1)

  // staging: wave w covers rows w*8..w*8+7 (+64) of each half; pre-swizzled source
  const int sg = (lane & 7) ^ ((lane >> 3) & 7);
  const u16* Abase = A  + (size_t)(bm + wid * 8 + (lane >> 3)) * lda + sg * 8;
  const u16* Bbase = Bm + (size_t)(bn + wid * 8 + (lane >> 3)) * ldb + sg * 8;

#define STGA(D, H, T) do {                                                   \
    const u16* _s = Abase + (size_t)((H) * 128) * lda + (size_t)(T) * 64;    \
    g2lds16(_s,                    &As[D][H][wid * 512]);                    \
    g2lds16(_s + (size_t)64 * lda, &As[D][H][4096 + wid * 512]);             \
  } while (0)
#define STGB(D, H, T) do {                                                   \
    const u16* _s = Bbase + (size_t)((H) * 128) * ldb + (size_t)(T) * 64;    \
    g2lds16(_s,                    &Bs[D][H][wid * 512]);                    \
    g2lds16(_s + (size_t)64 * ldb, &Bs[D][H][4096 + wid * 512]);             \
  } while (0)

  // bias preload FIRST: its 4 loads are oldest, drained by the prologue vmcnt(4)
  float bias_v[4] = {0.f, 0.f, 0.f, 0.f};
  if (BIAS_MODE == 1) {
#pragma unroll
    for (int g = 0; g < 4; ++g) bias_v[g] = bias[bn + wn + g * 64 + lr];
  }
  SCHED0();

  f32x4 acc[8][4];
  const f32x4 zero = {0.f, 0.f, 0.f, 0.f};
#pragma unroll
  for (int i = 0; i < 8; ++i)
#pragma unroll
    for (int j = 0; j < 4; ++j) acc[i][j] = zero;

  bf16x8 a_[4][2], b_[4][2];

#define RDA(D, AH) do {                                                      \
    _Pragma("unroll") for (int i = 0; i < 4; ++i) {                          \
      const int _o = (wm + i * 32 + lr) * 64;                                \
      a_[i][0] = *(const bf16x8*)&As[D][AH][_o + g0];                        \
      a_[i][1] = *(const bf16x8*)&As[D][AH][_o + g1];                        \
    } } while (0)
#define RDB(D, BH) do {                                                      \
    _Pragma("unroll") for (int j = 0; j < 2; ++j) {                          \
      const int _o = (wn + j * 64 + lr) * 64;                                \
      b_[(BH) * 2 + j][0] = *(const bf16x8*)&Bs[D][BH][_o + g0];             \
      b_[(BH) * 2 + j][1] = *(const bf16x8*)&Bs[D][BH][_o + g1];             \
    } } while (0)
#define MM(AH, BH) do {                                                      \
    __builtin_amdgcn_s_setprio(1);                                           \
    _Pragma("unroll") for (int i = 0; i < 4; ++i)                            \
    _Pragma("unroll") for (int j = 0; j < 2; ++j) {                          \
      acc[(AH) * 4 + i][(BH) * 2 + j] = __builtin_amdgcn_mfma_f32_16x16x32_bf16( \
          a_[i][0], b_[(BH) * 2 + j][0], acc[(AH) * 4 + i][(BH) * 2 + j], 0, 0, 0); \
      acc[(AH) * 4 + i][(BH) * 2 + j] = __builtin_amdgcn_mfma_f32_16x16x32_bf16( \
          a_[i][1], b_[(BH) * 2 + j][1], acc[(AH) * 4 + i][(BH) * 2 + j], 0, 0, 0); \
    }                                                                        \
    __builtin_amdgcn_s_setprio(0);                                           \
  } while (0)
#define MID() SCHED0(); BAR(); LGKM0; SCHED0()

  // prologue: tile0 all 4 halves, then tile1 A0,B1; drain tile0 BEFORE the barrier
  STGA(0, 0, 0); STGB(0, 1, 0); STGA(0, 1, 0); STGB(0, 0, 0);
  STGA(1, 0, 1); STGB(1, 1, 1);
  WAITV4;
  BAR();

  const int nt = K >> 6;  // even, >= 4
  for (int i = 0; i < nt / 2; ++i) {
    const int t1 = 2 * i + 1, t2 = 2 * i + 2, t3 = 2 * i + 3;
    const bool s2 = t2 < nt, s3 = t3 < nt;
    // p0 (d0, A0,B0)
    RDA(0, 0); RDB(0, 0);
    STGB(1, 0, t1);
    MID(); MM(0, 0); BAR();
    // p1 (d0, A0,B1)
    RDB(0, 1);
    STGA(1, 1, t1);
    MID(); MM(0, 1); BAR();
    // p2 (d0, A1,B1)
    RDA(0, 1);
    if (s2) STGA(0, 0, t2);
    MID(); MM(1, 1); BAR();
    // p3 (d0, A1,B0) — drain d1's stages BEFORE the end barrier
    if (s2) STGB(0, 1, t2);
    MID(); MM(1, 0);
    if (s2) { WAITV4; } else { WAITV0; }
    BAR();
    // p4 (d1, A0,B0)
    RDA(1, 0); RDB(1, 0);
    if (s2) STGA(0, 1, t2);
    MID(); MM(0, 0); BAR();
    // p5 (d1, A0,B1)
    RDB(1, 1);
    if (s2) STGB(0, 0, t2);
    MID(); MM(0, 1); BAR();
    // p6 (d1, A1,B1)
    RDA(1, 1);
    if (s3) STGA(1, 0, t3);
    MID(); MM(1, 1); BAR();
    // p7 (d1, A1,B0) — drain next d0's stages BEFORE the end barrier
    if (s3) STGB(1, 1, t3);
    MID(); MM(1, 0);
    if (s3) { WAITV4; }
    BAR();
  }
#undef STGA
#undef STGB
#undef RDA
#undef RDB
#undef MM
#undef MID
  SCHED0();

  if (SMAX) {
    // P = exp(alpha*s) bf16 + per-(row, col-block) partial sums -> smx
    float rs[8][4];
#pragma unroll
    for (int f = 0; f < 8; ++f) {
      const int row0 = bm + wm + f * 32 + lh * 4;
#pragma unroll
      for (int r = 0; r < 4; ++r) rs[f][r] = 0.f;
#pragma unroll
      for (int g = 0; g < 4; ++g) {
        const int col = bn + wn + g * 64 + lr;
#pragma unroll
        for (int r = 0; r < 4; ++r) {
          const float e = __expf(acc[f][g][r] * alpha);
          rs[f][r] += e;
          Cb[(size_t)(row0 + r) * ldc + col] = f2bf(e);
        }
      }
#pragma unroll
      for (int r = 0; r < 4; ++r) {
        float v = rs[f][r];
        v += __shfl_xor(v, 1, 64);
        v += __shfl_xor(v, 2, 64);
        v += __shfl_xor(v, 4, 64);
        v += __shfl_xor(v, 8, 64);
        rs[f][r] = v;
      }
    }
    // cross-wave (over wn) reduction: compile-time-predicated LDS writes
#pragma unroll
    for (int f = 0; f < 8; ++f)
#pragma unroll
      for (int r = 0; r < 4; ++r)
        if (lr == ((f << 1) | (r >> 1)))
          ps[wid & 3][wm + f * 32 + lh * 4 + r] = rs[f][r];
    __syncthreads();
    if (tid < 256) {
      const float tot = ps[0][tid] + ps[1][tid] + ps[2][tid] + ps[3][tid];
      smx[((size_t)(bz * 16 + bx) << 12) + bm + tid] = tot;
    }
  } else {
#pragma unroll
    for (int f = 0; f < 8; ++f) {
      const int row0 = bm + wm + f * 32 + lh * 4;
#pragma unroll
      for (int g = 0; g < 4; ++g) {
        const int col = bn + wn + g * 64 + lr;
#pragma unroll
        for (int r = 0; r < 4; ++r)
          Cb[(size_t)(row0 + r) * ldc + col] = f2bf(acc[f][g][r] * alpha + bias_v[g]);
      }
    }
  }
}

// ---------------- 128x128 GEMM (V-proj and out-proj) ----------------
// BCOMB=1: B-operand is the fp32 sum of two bf16 psum buffers (Bg, Bg2), added
// during reg-staged B-staging (replaces the separate add_scale pass).
// OUT_MODE=1: fp32 out[b,o,s] = acc*lscale[n] + bias[m] + xres, n = b*S+s.
#define GBM 128
#define GBN 128
#define GBK 64

template <int BIAS_MODE, int OUT_MODE, int BCOMB>
__global__ __launch_bounds__(256) void gemm_abT(
    const u16* __restrict__ Ag, int lda, long sA,
    const u16* __restrict__ Bg, int ldb, long sB,
    void* __restrict__ Cg, int ldc, long sC,
    const float* __restrict__ bias, float alpha,
    const float* __restrict__ xres, const float* __restrict__ lscale,
    const u16* __restrict__ Bg2, int K) {
  __shared__ u16 As[GBM * GBK];
  __shared__ u16 Bs[GBN * GBK];
  const int bz = blockIdx.z;
  const u16* A    = Ag + (size_t)bz * sA;
  const u16* Bmat = Bg + (size_t)bz * sB;
  const int bm = blockIdx.y * GBM, bn = blockIdx.x * GBN;
  const int tid = threadIdx.x;
  const int wid = tid >> 6, lane = tid & 63;
  const int wm = (wid >> 1) * 64, wn = (wid & 1) * 64;
  const int lr = lane & 15, lh = lane >> 4;
  const int srow = lane >> 3, scol = (lane & 7) * 8;

  f32x4 acc[4][4];
  const f32x4 zero = {0.f, 0.f, 0.f, 0.f};
#pragma unroll
  for (int i = 0; i < 4; ++i)
#pragma unroll
    for (int j = 0; j < 4; ++j) acc[i][j] = zero;

  for (int k0 = 0; k0 < K; k0 += GBK) {
    __syncthreads();
#pragma unroll
    for (int i = 0; i < 4; ++i) {
      const int chunk = wid * 4 + i;
      const int row   = chunk * 8 + srow;
      g2lds16(A + (size_t)(bm + row) * lda + (k0 + scol), &As[chunk * 512]);
      if (BCOMB == 0) {
        g2lds16(Bmat + (size_t)(bn + row) * ldb + (k0 + scol), &Bs[chunk * 512]);
      } else {
        const size_t boff = (size_t)(bn + row) * ldb + (k0 + scol);
        const uint4 u0 = *(const uint4*)(Bmat + boff);
        const uint4 u1 = *(const uint4*)(Bg2 + boff);
        const unsigned* p0 = (const unsigned*)&u0;
        const unsigned* p1 = (const unsigned*)&u1;
        unsigned rr[4];
#pragma unroll
        for (int k = 0; k < 4; ++k) {
          const float lo = bf2f((u16)(p0[k] & 0xffffu)) + bf2f((u16)(p1[k] & 0xffffu));
          const float hi = bf2f((u16)(p0[k] >> 16)) + bf2f((u16)(p1[k] >> 16));
          rr[k] = (unsigned)f2bf(lo) | ((unsigned)f2bf(hi) << 16);
        }
        *(uint4*)&Bs[chunk * 512 + lane * 8] = *(const uint4*)rr;
      }
    }
    __syncthreads();
#pragma unroll
    for (int ks = 0; ks < 2; ++ks) {
      bf16x8 a_[4], b_[4];
#pragma unroll
      for (int m = 0; m < 4; ++m)
        a_[m] = *(const bf16x8*)&As[(wm + m * 16 + lr) * GBK + ks * 32 + lh * 8];
#pragma unroll
      for (int n = 0; n < 4; ++n)
        b_[n] = *(const bf16x8*)&Bs[(wn + n * 16 + lr) * GBK + ks * 32 + lh * 8];
#pragma unroll
      for (int m = 0; m < 4; ++m)
#pragma unroll
        for (int n = 0; n < 4; ++n)
          acc[m][n] = __builtin_amdgcn_mfma_f32_16x16x32_bf16(a_[m], b_[n], acc[m][n], 0, 0, 0);
    }
  }

  if (OUT_MODE == 0) {
    u16* Cb = (u16*)Cg + (size_t)bz * sC;
#pragma unroll
    for (int m = 0; m < 4; ++m) {
      const int row0 = bm + wm + m * 16 + lh * 4;
#pragma unroll
      for (int n = 0; n < 4; ++n) {
        const int col = bn + wn + n * 16 + lr;
        float bn_ = (BIAS_MODE == 1) ? bias[col] : 0.f;
#pragma unroll
        for (int r = 0; r < 4; ++r) {
          float bb = (BIAS_MODE == 2) ? bias[row0 + r] : bn_;
          Cb[(size_t)(row0 + r) * ldc + col] = f2bf(acc[m][n][r] * alpha + bb);
        }
      }
    }
  } else {
    float* Ob = (float*)Cg;
#pragma unroll
    for (int m = 0; m < 4; ++m) {
      const int row0 = bm + wm + m * 16 + lh * 4;
#pragma unroll
      for (int n = 0; n < 4; ++n) {
        const int col = bn + wn + n * 16 + lr;
        const int bb = col >> 12, sp = col & (S_ - 1);
        const float lsc = lscale[col];
#pragma unroll
        for (int r = 0; r < 4; ++r) {
          const int o = row0 + r;
          const size_t idx = ((size_t)bb * C_ + o) * S_ + sp;
          Ob[idx] = acc[m][n][r] * lsc + bias[o] + xres[idx];
        }
      }
    }
  }
}

extern "C" void kernel_launch(void* const* d_in, const int* in_sizes, int n_in,
                              void* d_out, int out_size, void* d_ws, size_t ws_size,
                              hipStream_t stream) {
  const float* x     = (const float*)d_in[0];
  const float* gamma = (const float*)d_in[1];
  const float* beta  = (const float*)d_in[2];
  const float* wq = (const float*)d_in[3];
  const float* bq = (const float*)d_in[4];
  const float* wk = (const float*)d_in[5];
  const float* bk = (const float*)d_in[6];
  const float* wv = (const float*)d_in[7];
  const float* bv = (const float*)d_in[8];
  const float* wo = (const float*)d_in[9];
  const float* bo = (const float*)d_in[10];
  float* out = (float*)d_out;

  // ws: stats 1KB | weights bf16 4x512KB | bqk 4KB | ht 16MB | qkt 32MB | vv 16MB
  //     | sc 128MB | partials 1MB | Lr 64KB
  char* ws = (char*)d_ws;
  float* stats = (float*)ws;
  u16* wqb = (u16*)(ws + 1024);
  u16* wkb = wqb + 262144;   // contiguous after wqb -> [wq;wk] is one 1024x512 matrix
  u16* wvb = wkb + 262144;
  u16* wob = wvb + 262144;
  float* bqk = (float*)(wob + 262144);
  u16* ht  = (u16*)((char*)bqk + 4096);  // [B*S, C]
  u16* qkt = ht + 8388608;               // [B*S, 1024] (q|k); later PV psum halves
  u16* vv  = qkt + 16777216;             // [C, B*S]
  u16* sc  = vv + 8388608;               // [B, S, S] exp(scores)
  float* partials = (float*)(sc + 67108864);  // [B][16][4096]
  float* Lr = partials + 262144;              // [B][4096]

  f32_to_bf16<<<1024, 256, 0, stream>>>(wq, wqb, 262144);
  f32_to_bf16<<<1024, 256, 0, stream>>>(wk, wkb, 262144);
  f32_to_bf16<<<1024, 256, 0, stream>>>(wv, wvb, 262144);
  f32_to_bf16<<<1024, 256, 0, stream>>>(wo, wob, 262144);
  concat_bias<<<4, 256, 0, stream>>>(bq, bk, bqk);

  gn_stats<<<128, 256, 0, stream>>>(x, stats);
  gn_apply_t<<<dim3(128, 16, 4), dim3(32, 8), 0, stream>>>(x, gamma, beta, stats, ht);

  // fused Q|K projection: qkt[bs, 0:512]=Q, [512:1024]=K   (256 blocks)
  gemm8p<1, 0, 0><<<dim3(4, 64, 1), 512, 0, stream>>>(ht, 512, 0, wqb, 512, 0,
                                                      qkt, 1024, 0, bqk, 1.f, 512, nullptr);
  // V[c, b*S+s]: bias per m (=c)                            (512 blocks)
  gemm_abT<2, 0, 0><<<dim3(128, 4, 1), 256, 0, stream>>>(wvb, 512, 0, ht, 512, 0,
                                                         vv, 16384, 0, bv, 1.f,
                                                         nullptr, nullptr, nullptr, 512);
  // P[b,i,j] = exp(scale * Q.K) + row-sum partials          (1024 blocks)
  gemm8p<0, 0, 1><<<dim3(16, 16, 4), 512, 0, stream>>>(qkt, 1024, 4194304, qkt + 512, 1024, 4194304,
                                                       sc, 4096, 16777216, nullptr,
                                                       0.04419417382415922f, 512, partials);
  reduce_l<<<64, 256, 0, stream>>>(partials, Lr);
  // PV split-K=2 on unnormalized P: psums in qkt halves     (256 blocks)
  gemm8p<0, 1, 0><<<dim3(2, 16, 8), 512, 0, stream>>>(sc, 4096, 0, vv, 16384, 0,
                                                      qkt, 512, 0, nullptr, 1.f, 2048, nullptr);
  // out[b,o,s] = (Wo @ (psum0+psum1)) * Lr[bs] + bo + x      (512 blocks)
  // psum add folded into B-staging (BCOMB); 1/l folded into epilogue.
  gemm_abT<2, 1, 1><<<dim3(128, 4, 1), 256, 0, stream>>>(wob, 512, 0, qkt, 512, 0,
                                                         out, 0, 0, bo, 1.f,
                                                         x, Lr, qkt + 8388608, 512);
}

// Round 12
// 288.576 us; speedup vs baseline: 1.0751x; 1.0077x over previous
//
#include <hip/hip_runtime.h>

#define B_   4
#define C_   512
#define S_   4096
#define G_   32
#define CPG_ 16
#define EPS_ 1e-6f

typedef unsigned short u16;
typedef __bf16 bf16x8 __attribute__((ext_vector_type(8)));
typedef float  f32x4  __attribute__((ext_vector_type(4)));

__device__ __forceinline__ u16 f2bf(float f) {
  unsigned u = __float_as_uint(f);
  u += 0x7fffu + ((u >> 16) & 1u);   // RNE
  return (u16)(u >> 16);
}
__device__ __forceinline__ float bf2f(u16 h) {
  return __uint_as_float((unsigned)h << 16);
}

__device__ __forceinline__ void g2lds16(const void* g, void* l) {
  __builtin_amdgcn_global_load_lds(
      (const __attribute__((address_space(1))) void*)g,
      (__attribute__((address_space(3))) void*)l, 16, 0, 0);
}

#define BAR()    __builtin_amdgcn_s_barrier()
#define SCHED0() __builtin_amdgcn_sched_barrier(0)
#define WAITV4   asm volatile("s_waitcnt vmcnt(4)" ::: "memory")
#define WAITV0   asm volatile("s_waitcnt vmcnt(0)" ::: "memory")

// chunked XCD swizzle (bijective when nwg % 8 == 0 — all grids here satisfy it)
__device__ __forceinline__ void xcd_swz(int& bx, int& by, int& bz) {
  const int gx = gridDim.x, gy = gridDim.y;
  const int nwg = gx * gy * (int)gridDim.z;
  const int flat = blockIdx.x + gx * (blockIdx.y + gy * blockIdx.z);
  const int q = nwg >> 3;
  const int nf = (flat & 7) * q + (flat >> 3);
  bx = nf % gx;
  const int r = nf / gx;
  by = r % gy;
  bz = r / gy;
}

// ---------------- fp32 -> bf16 weight conversion ----------------
__global__ __launch_bounds__(256) void f32_to_bf16(const float* __restrict__ in,
                                                   u16* __restrict__ out, int n) {
  int i = blockIdx.x * 256 + threadIdx.x;
  if (i < n) out[i] = f2bf(in[i]);
}

__global__ __launch_bounds__(256) void concat_bias(const float* __restrict__ a,
                                                   const float* __restrict__ b,
                                                   float* __restrict__ o) {
  int i = blockIdx.x * 256 + threadIdx.x;  // grid 4 -> 1024
  o[i] = (i < 512) ? a[i] : b[i - 512];
}

// ---------------- softmax denominator: Lr[b,i] = 1/sum_jb partial ----------------
__global__ __launch_bounds__(256) void reduce_l(const float* __restrict__ p,
                                                float* __restrict__ lr) {
  const int i = blockIdx.x * 256 + threadIdx.x;   // 16384 = B*S
  const int b = i >> 12, row = i & 4095;
  float s = 0.f;
#pragma unroll
  for (int jb = 0; jb < 16; ++jb) s += p[((size_t)(b * 16 + jb) << 12) + row];
  lr[i] = 1.f / s;
}

// ---------------- GroupNorm stats: one block per (b,g) ----------------
__global__ __launch_bounds__(256) void gn_stats(const float* __restrict__ x,
                                                float* __restrict__ stats) {
  const int bg = blockIdx.x;
  const float4* p4 = (const float4*)(x + (size_t)bg * (CPG_ * S_));
  float s = 0.f, ss = 0.f;
  const int tid = threadIdx.x;
  for (int i = tid; i < CPG_ * S_ / 4; i += 256) {
    float4 v = p4[i];
    s  += v.x + v.y + v.z + v.w;
    ss += v.x * v.x + v.y * v.y + v.z * v.z + v.w * v.w;
  }
#pragma unroll
  for (int o = 32; o; o >>= 1) { s += __shfl_xor(s, o, 64); ss += __shfl_xor(ss, o, 64); }
  __shared__ float sm[8];
  const int wid = tid >> 6, lane = tid & 63;
  if (lane == 0) { sm[wid * 2] = s; sm[wid * 2 + 1] = ss; }
  __syncthreads();
  if (tid == 0) {
    s  = sm[0] + sm[2] + sm[4] + sm[6];
    ss = sm[1] + sm[3] + sm[5] + sm[7];
    const float inv = 1.f / (float)(CPG_ * S_);
    float mu = s * inv;
    float var = ss * inv - mu * mu;
    stats[bg * 2]     = mu;
    stats[bg * 2 + 1] = rsqrtf(var + EPS_);
  }
}

// ---------------- normalize + transpose: x[b,c,s] -> ht[b*s, c] bf16 ----------------
__global__ __launch_bounds__(256) void gn_apply_t(const float* __restrict__ x,
                                                  const float* __restrict__ gamma,
                                                  const float* __restrict__ beta,
                                                  const float* __restrict__ stats,
                                                  u16* __restrict__ ht) {
  __shared__ float tile[32][33];
  const int b = blockIdx.z, c0 = blockIdx.y * 32, s0 = blockIdx.x * 32;
  const int tx = threadIdx.x, ty = threadIdx.y;
#pragma unroll
  for (int i = 0; i < 4; ++i) {
    const int c  = c0 + ty + i * 8;
    const float mu = stats[(b * G_ + (c >> 4)) * 2];
    const float rs = stats[(b * G_ + (c >> 4)) * 2 + 1];
    const float v  = x[((size_t)b * C_ + c) * S_ + s0 + tx];
    tile[ty + i * 8][tx] = (v - mu) * rs * gamma[c] + beta[c];
  }
  __syncthreads();
#pragma unroll
  for (int i = 0; i < 4; ++i) {
    const int s = s0 + ty + i * 8;
    ht[((size_t)b * S_ + s) * C_ + c0 + tx] = f2bf(tile[tx][ty + i * 8]);
  }
}

// ======= 256x256 8-phase GEMM — single barrier/phase, compiler-counted lgkm =======
// C[m,n] = alpha * sum_k A[m,k]*B[n,k] (+bias[n]); A,B bf16 K-contiguous.
// 512 thr = 8 waves (2M x 4N), strided frags: m-frag f at wm+f*32, n-frag g at
// wn+g*64. LDS As/Bs[2 dbuf][2 half][128][64] u16; swizzle phys granule = g^(row&7).
// Phase = {ds_reads; stage; [counted vmcnt]; BAR; setprio(1) MFMA setprio(0)}.
// NO hard lgkmcnt(0): compiler emits per-fragment counted lgkm waits so MFMA
// starts as soon as its first frags land, and next phase's reads/stages issue
// under the MFMA tail (the m97/m201 overlap this kernel previously serialized).
// Single-barrier ledger (hand-verified): every buffer's last ds_read is >=2
// barriers before its re-stage (in-order issue => reads consumed before the
// owning wave crosses the following barrier). vmcnt(4) at p3/p7 ends (asm
// volatile, unhoistable) drains exactly the 8 loads of the dbuf read next.
// ZMODE 1 = PV split-K: bz -> (b = bz>>1, kh = bz&1), hardcoded offsets.
// SMAX 1 = scores epilogue: write exp(alpha*acc) bf16 + per-block row-sum partials.
template <int BIAS_MODE, int ZMODE, int SMAX>
__global__ __launch_bounds__(512, 2) void gemm8p(
    const u16* __restrict__ Ag, int lda, long sA,
    const u16* __restrict__ Bg, int ldb, long sB,
    u16* __restrict__ Cg, int ldc, long sC,
    const float* __restrict__ bias, float alpha, int K,
    float* __restrict__ smx) {
  __shared__ u16 As[2][2][8192];
  __shared__ u16 Bs[2][2][8192];
  __shared__ float ps[4][256];
  int bx, by, bz;
  xcd_swz(bx, by, bz);
  const u16 *A, *Bm;
  u16* Cb;
  if (ZMODE == 0) {
    A = Ag + (size_t)bz * sA; Bm = Bg + (size_t)bz * sB; Cb = Cg + (size_t)bz * sC;
  } else {  // PV split-K: A = P[b], cols kh*2048+; B = V rows, cols b*4096+kh*2048+
    const int b = bz >> 1, kh = bz & 1;
    A  = Ag + (size_t)b * 16777216 + (size_t)kh * 2048;
    Bm = Bg + (size_t)b * 4096 + (size_t)kh * 2048;
    Cb = Cg + (size_t)kh * 8388608 + (size_t)b * 2097152;
  }
  const int bm = by * 256, bn = bx * 256;
  const int tid = threadIdx.x;
  const int wid = tid >> 6, lane = tid & 63;
  const int wm = (wid >> 2) * 16, wn = (wid & 3) * 16;
  const int lr = lane & 15, lh = lane >> 4;
  const int x7 = lr & 7;
  const int g0 = (lh ^ x7) * 8, g1 = ((4 | lh) ^ x7) * 8;  // swizzled granule offs (kh=0/1)

  // staging: wave w covers rows w*8..w*8+7 (+64) of each half; pre-swizzled source
  const int sg = (lane & 7) ^ ((lane >> 3) & 7);
  const u16* Abase = A  + (size_t)(bm + wid * 8 + (lane >> 3)) * lda + sg * 8;
  const u16* Bbase = Bm + (size_t)(bn + wid * 8 + (lane >> 3)) * ldb + sg * 8;

#define STGA(D, H, T) do {                                                   \
    const u16* _s = Abase + (size_t)((H) * 128) * lda + (size_t)(T) * 64;    \
    g2lds16(_s,                    &As[D][H][wid * 512]);                    \
    g2lds16(_s + (size_t)64 * lda, &As[D][H][4096 + wid * 512]);             \
  } while (0)
#define STGB(D, H, T) do {                                                   \
    const u16* _s = Bbase + (size_t)((H) * 128) * ldb + (size_t)(T) * 64;    \
    g2lds16(_s,                    &Bs[D][H][wid * 512]);                    \
    g2lds16(_s + (size_t)64 * ldb, &Bs[D][H][4096 + wid * 512]);             \
  } while (0)

  // bias preload FIRST: its 4 loads are oldest, drained by the prologue vmcnt(4)
  float bias_v[4] = {0.f, 0.f, 0.f, 0.f};
  if (BIAS_MODE == 1) {
#pragma unroll
    for (int g = 0; g < 4; ++g) bias_v[g] = bias[bn + wn + g * 64 + lr];
  }
  SCHED0();

  f32x4 acc[8][4];
  const f32x4 zero = {0.f, 0.f, 0.f, 0.f};
#pragma unroll
  for (int i = 0; i < 8; ++i)
#pragma unroll
    for (int j = 0; j < 4; ++j) acc[i][j] = zero;

  bf16x8 a_[4][2], b_[4][2];

#define RDA(D, AH) do {                                                      \
    _Pragma("unroll") for (int i = 0; i < 4; ++i) {                          \
      const int _o = (wm + i * 32 + lr) * 64;                                \
      a_[i][0] = *(const bf16x8*)&As[D][AH][_o + g0];                        \
      a_[i][1] = *(const bf16x8*)&As[D][AH][_o + g1];                        \
    } } while (0)
#define RDB(D, BH) do {                                                      \
    _Pragma("unroll") for (int j = 0; j < 2; ++j) {                          \
      const int _o = (wn + j * 64 + lr) * 64;                                \
      b_[(BH) * 2 + j][0] = *(const bf16x8*)&Bs[D][BH][_o + g0];             \
      b_[(BH) * 2 + j][1] = *(const bf16x8*)&Bs[D][BH][_o + g1];             \
    } } while (0)
#define MM(AH, BH) do {                                                      \
    __builtin_amdgcn_s_setprio(1);                                           \
    _Pragma("unroll") for (int i = 0; i < 4; ++i)                            \
    _Pragma("unroll") for (int j = 0; j < 2; ++j) {                          \
      acc[(AH) * 4 + i][(BH) * 2 + j] = __builtin_amdgcn_mfma_f32_16x16x32_bf16( \
          a_[i][0], b_[(BH) * 2 + j][0], acc[(AH) * 4 + i][(BH) * 2 + j], 0, 0, 0); \
      acc[(AH) * 4 + i][(BH) * 2 + j] = __builtin_amdgcn_mfma_f32_16x16x32_bf16( \
          a_[i][1], b_[(BH) * 2 + j][1], acc[(AH) * 4 + i][(BH) * 2 + j], 0, 0, 0); \
    }                                                                        \
    __builtin_amdgcn_s_setprio(0);                                           \
  } while (0)

  // prologue: tile0 all 4 halves, then tile1 A0,B1; drain tile0 BEFORE the barrier
  STGA(0, 0, 0); STGB(0, 1, 0); STGA(0, 1, 0); STGB(0, 0, 0);
  STGA(1, 0, 1); STGB(1, 1, 1);
  WAITV4;
  BAR();

  const int nt = K >> 6;  // even, >= 4
  for (int i = 0; i < nt / 2; ++i) {
    const int t1 = 2 * i + 1, t2 = 2 * i + 2, t3 = 2 * i + 3;
    const bool s2 = t2 < nt, s3 = t3 < nt;
    // p0 (d0, A0,B0)
    RDA(0, 0); RDB(0, 0);
    STGB(1, 0, t1);
    BAR(); MM(0, 0);
    // p1 (d0, A0,B1)
    RDB(0, 1);
    STGA(1, 1, t1);
    BAR(); MM(0, 1);
    // p2 (d0, A1,B1)
    RDA(0, 1);
    if (s2) STGA(0, 0, t2);
    BAR(); MM(1, 1);
    // p3 (d0, A1,B0) — counted drain of d1's stages before the phase barrier
    if (s2) STGB(0, 1, t2);
    if (s2) { WAITV4; } else { WAITV0; }
    BAR(); MM(1, 0);
    // p4 (d1, A0,B0)
    RDA(1, 0); RDB(1, 0);
    if (s2) STGA(0, 1, t2);
    BAR(); MM(0, 0);
    // p5 (d1, A0,B1)
    RDB(1, 1);
    if (s2) STGB(0, 0, t2);
    BAR(); MM(0, 1);
    // p6 (d1, A1,B1)
    RDA(1, 1);
    if (s3) STGA(1, 0, t3);
    BAR(); MM(1, 1);
    // p7 (d1, A1,B0) — counted drain of next d0's stages before the phase barrier
    if (s3) STGB(1, 1, t3);
    if (s3) { WAITV4; }
    BAR(); MM(1, 0);
  }
#undef STGA
#undef STGB
#undef RDA
#undef RDB
#undef MM
  SCHED0();

  if (SMAX) {
    // P = exp(alpha*s) bf16 + per-(row, col-block) partial sums -> smx
    float rs[8][4];
#pragma unroll
    for (int f = 0; f < 8; ++f) {
      const int row0 = bm + wm + f * 32 + lh * 4;
#pragma unroll
      for (int r = 0; r < 4; ++r) rs[f][r] = 0.f;
#pragma unroll
      for (int g = 0; g < 4; ++g) {
        const int col = bn + wn + g * 64 + lr;
#pragma unroll
        for (int r = 0; r < 4; ++r) {
          const float e = __expf(acc[f][g][r] * alpha);
          rs[f][r] += e;
          Cb[(size_t)(row0 + r) * ldc + col] = f2bf(e);
        }
      }
#pragma unroll
      for (int r = 0; r < 4; ++r) {
        float v = rs[f][r];
        v += __shfl_xor(v, 1, 64);
        v += __shfl_xor(v, 2, 64);
        v += __shfl_xor(v, 4, 64);
        v += __shfl_xor(v, 8, 64);
        rs[f][r] = v;
      }
    }
    // cross-wave (over wn) reduction: compile-time-predicated LDS writes
#pragma unroll
    for (int f = 0; f < 8; ++f)
#pragma unroll
      for (int r = 0; r < 4; ++r)
        if (lr == ((f << 1) | (r >> 1)))
          ps[wid & 3][wm + f * 32 + lh * 4 + r] = rs[f][r];
    __syncthreads();
    if (tid < 256) {
      const float tot = ps[0][tid] + ps[1][tid] + ps[2][tid] + ps[3][tid];
      smx[((size_t)(bz * 16 + bx) << 12) + bm + tid] = tot;
    }
  } else {
#pragma unroll
    for (int f = 0; f < 8; ++f) {
      const int row0 = bm + wm + f * 32 + lh * 4;
#pragma unroll
      for (int g = 0; g < 4; ++g) {
        const int col = bn + wn + g * 64 + lr;
#pragma unroll
        for (int r = 0; r < 4; ++r)
          Cb[(size_t)(row0 + r) * ldc + col] = f2bf(acc[f][g][r] * alpha + bias_v[g]);
      }
    }
  }
}

// ---------------- 128x128 GEMM (V-proj and out-proj) ----------------
// BCOMB=1: B-operand is the fp32 sum of two bf16 psum buffers (Bg, Bg2), added
// during reg-staged B-staging (replaces the separate add_scale pass).
// OUT_MODE=1: fp32 out[b,o,s] = acc*lscale[n] + bias[m] + xres, n = b*S+s.
#define GBM 128
#define GBN 128
#define GBK 64

template <int BIAS_MODE, int OUT_MODE, int BCOMB>
__global__ __launch_bounds__(256) void gemm_abT(
    const u16* __restrict__ Ag, int lda, long sA,
    const u16* __restrict__ Bg, int ldb, long sB,
    void* __restrict__ Cg, int ldc, long sC,
    const float* __restrict__ bias, float alpha,
    const float* __restrict__ xres, const float* __restrict__ lscale,
    const u16* __restrict__ Bg2, int K) {
  __shared__ u16 As[GBM * GBK];
  __shared__ u16 Bs[GBN * GBK];
  const int bz = blockIdx.z;
  const u16* A    = Ag + (size_t)bz * sA;
  const u16* Bmat = Bg + (size_t)bz * sB;
  const int bm = blockIdx.y * GBM, bn = blockIdx.x * GBN;
  const int tid = threadIdx.x;
  const int wid = tid >> 6, lane = tid & 63;
  const int wm = (wid >> 1) * 64, wn = (wid & 1) * 64;
  const int lr = lane & 15, lh = lane >> 4;
  const int srow = lane >> 3, scol = (lane & 7) * 8;

  f32x4 acc[4][4];
  const f32x4 zero = {0.f, 0.f, 0.f, 0.f};
#pragma unroll
  for (int i = 0; i < 4; ++i)
#pragma unroll
    for (int j = 0; j < 4; ++j) acc[i][j] = zero;

  for (int k0 = 0; k0 < K; k0 += GBK) {
    __syncthreads();
#pragma unroll
    for (int i = 0; i < 4; ++i) {
      const int chunk = wid * 4 + i;
      const int row   = chunk * 8 + srow;
      g2lds16(A + (size_t)(bm + row) * lda + (k0 + scol), &As[chunk * 512]);
      if (BCOMB == 0) {
        g2lds16(Bmat + (size_t)(bn + row) * ldb + (k0 + scol), &Bs[chunk * 512]);
      } else {
        const size_t boff = (size_t)(bn + row) * ldb + (k0 + scol);
        const uint4 u0 = *(const uint4*)(Bmat + boff);
        const uint4 u1 = *(const uint4*)(Bg2 + boff);
        const unsigned* p0 = (const unsigned*)&u0;
        const unsigned* p1 = (const unsigned*)&u1;
        unsigned rr[4];
#pragma unroll
        for (int k = 0; k < 4; ++k) {
          const float lo = bf2f((u16)(p0[k] & 0xffffu)) + bf2f((u16)(p1[k] & 0xffffu));
          const float hi = bf2f((u16)(p0[k] >> 16)) + bf2f((u16)(p1[k] >> 16));
          rr[k] = (unsigned)f2bf(lo) | ((unsigned)f2bf(hi) << 16);
        }
        *(uint4*)&Bs[chunk * 512 + lane * 8] = *(const uint4*)rr;
      }
    }
    __syncthreads();
#pragma unroll
    for (int ks = 0; ks < 2; ++ks) {
      bf16x8 a_[4], b_[4];
#pragma unroll
      for (int m = 0; m < 4; ++m)
        a_[m] = *(const bf16x8*)&As[(wm + m * 16 + lr) * GBK + ks * 32 + lh * 8];
#pragma unroll
      for (int n = 0; n < 4; ++n)
        b_[n] = *(const bf16x8*)&Bs[(wn + n * 16 + lr) * GBK + ks * 32 + lh * 8];
#pragma unroll
      for (int m = 0; m < 4; ++m)
#pragma unroll
        for (int n = 0; n < 4; ++n)
          acc[m][n] = __builtin_amdgcn_mfma_f32_16x16x32_bf16(a_[m], b_[n], acc[m][n], 0, 0, 0);
    }
  }

  if (OUT_MODE == 0) {
    u16* Cb = (u16*)Cg + (size_t)bz * sC;
#pragma unroll
    for (int m = 0; m < 4; ++m) {
      const int row0 = bm + wm + m * 16 + lh * 4;
#pragma unroll
      for (int n = 0; n < 4; ++n) {
        const int col = bn + wn + n * 16 + lr;
        float bn_ = (BIAS_MODE == 1) ? bias[col] : 0.f;
#pragma unroll
        for (int r = 0; r < 4; ++r) {
          float bb = (BIAS_MODE == 2) ? bias[row0 + r] : bn_;
          Cb[(size_t)(row0 + r) * ldc + col] = f2bf(acc[m][n][r] * alpha + bb);
        }
      }
    }
  } else {
    float* Ob = (float*)Cg;
#pragma unroll
    for (int m = 0; m < 4; ++m) {
      const int row0 = bm + wm + m * 16 + lh * 4;
#pragma unroll
      for (int n = 0; n < 4; ++n) {
        const int col = bn + wn + n * 16 + lr;
        const int bb = col >> 12, sp = col & (S_ - 1);
        const float lsc = lscale[col];
#pragma unroll
        for (int r = 0; r < 4; ++r) {
          const int o = row0 + r;
          const size_t idx = ((size_t)bb * C_ + o) * S_ + sp;
          Ob[idx] = acc[m][n][r] * lsc + bias[o] + xres[idx];
        }
      }
    }
  }
}

extern "C" void kernel_launch(void* const* d_in, const int* in_sizes, int n_in,
                              void* d_out, int out_size, void* d_ws, size_t ws_size,
                              hipStream_t stream) {
  const float* x     = (const float*)d_in[0];
  const float* gamma = (const float*)d_in[1];
  const float* beta  = (const float*)d_in[2];
  const float* wq = (const float*)d_in[3];
  const float* bq = (const float*)d_in[4];
  const float* wk = (const float*)d_in[5];
  const float* bk = (const float*)d_in[6];
  const float* wv = (const float*)d_in[7];
  const float* bv = (const float*)d_in[8];
  const float* wo = (const float*)d_in[9];
  const float* bo = (const float*)d_in[10];
  float* out = (float*)d_out;

  // ws: stats 1KB | weights bf16 4x512KB | bqk 4KB | ht 16MB | qkt 32MB | vv 16MB
  //     | sc 128MB | partials 1MB | Lr 64KB
  char* ws = (char*)d_ws;
  float* stats = (float*)ws;
  u16* wqb = (u16*)(ws + 1024);
  u16* wkb = wqb + 262144;   // contiguous after wqb -> [wq;wk] is one 1024x512 matrix
  u16* wvb = wkb + 262144;
  u16* wob = wvb + 262144;
  float* bqk = (float*)(wob + 262144);
  u16* ht  = (u16*)((char*)bqk + 4096);  // [B*S, C]
  u16* qkt = ht + 8388608;               // [B*S, 1024] (q|k); later PV psum halves
  u16* vv  = qkt + 16777216;             // [C, B*S]
  u16* sc  = vv + 8388608;               // [B, S, S] exp(scores)
  float* partials = (float*)(sc + 67108864);  // [B][16][4096]
  float* Lr = partials + 262144;              // [B][4096]

  f32_to_bf16<<<1024, 256, 0, stream>>>(wq, wqb, 262144);
  f32_to_bf16<<<1024, 256, 0, stream>>>(wk, wkb, 262144);
  f32_to_bf16<<<1024, 256, 0, stream>>>(wv, wvb, 262144);
  f32_to_bf16<<<1024, 256, 0, stream>>>(wo, wob, 262144);
  concat_bias<<<4, 256, 0, stream>>>(bq, bk, bqk);

  gn_stats<<<128, 256, 0, stream>>>(x, stats);
  gn_apply_t<<<dim3(128, 16, 4), dim3(32, 8), 0, stream>>>(x, gamma, beta, stats, ht);

  // fused Q|K projection: qkt[bs, 0:512]=Q, [512:1024]=K   (256 blocks)
  gemm8p<1, 0, 0><<<dim3(4, 64, 1), 512, 0, stream>>>(ht, 512, 0, wqb, 512, 0,
                                                      qkt, 1024, 0, bqk, 1.f, 512, nullptr);
  // V[c, b*S+s]: bias per m (=c)                            (512 blocks)
  gemm_abT<2, 0, 0><<<dim3(128, 4, 1), 256, 0, stream>>>(wvb, 512, 0, ht, 512, 0,
                                                         vv, 16384, 0, bv, 1.f,
                                                         nullptr, nullptr, nullptr, 512);
  // P[b,i,j] = exp(scale * Q.K) + row-sum partials          (1024 blocks)
  gemm8p<0, 0, 1><<<dim3(16, 16, 4), 512, 0, stream>>>(qkt, 1024, 4194304, qkt + 512, 1024, 4194304,
                                                       sc, 4096, 16777216, nullptr,
                                                       0.04419417382415922f, 512, partials);
  reduce_l<<<64, 256, 0, stream>>>(partials, Lr);
  // PV split-K=2 on unnormalized P: psums in qkt halves     (256 blocks)
  gemm8p<0, 1, 0><<<dim3(2, 16, 8), 512, 0, stream>>>(sc, 4096, 0, vv, 16384, 0,
                                                      qkt, 512, 0, nullptr, 1.f, 2048, nullptr);
  // out[b,o,s] = (Wo @ (psum0+psum1)) * Lr[bs] + bo + x      (512 blocks)
  gemm_abT<2, 1, 1><<<dim3(128, 4, 1), 256, 0, stream>>>(wob, 512, 0, qkt, 512, 0,
                                                         out, 0, 0, bo, 1.f,
                                                         x, Lr, qkt + 8388608, 512);
}